// Round 2
// baseline (332.620 us; speedup 1.0000x reference)
//
#include <hip/hip_runtime.h>
#include <hip/hip_bf16.h>

// Problem constants (B,T,H fixed by setup_inputs)
#define B_ 16
#define T_ 8192
#define H_ 256
#define M_ (B_ * T_)   // 131072 rows
#define K_ 512         // concatenated K: [x | means]
#define STRIDE_ 8      // window over [max(0,t-8), t], count = min(t+1, 9)

typedef __bf16 bf16x8 __attribute__((ext_vector_type(8)));
typedef float f32x4 __attribute__((ext_vector_type(4)));

// round-to-nearest-even fp32 -> bf16 bits
__device__ __forceinline__ unsigned short f2bf(float f) {
  unsigned u = __builtin_bit_cast(unsigned, f);
  u += 0x7fffu + ((u >> 16) & 1u);
  return (unsigned short)(u >> 16);
}

// async global -> LDS, 16 bytes per lane (global_load_lds_dwordx4)
__device__ __forceinline__ void load_lds16(const void* g, void* l) {
  __builtin_amdgcn_global_load_lds(
      (const __attribute__((address_space(1))) void*)g,
      (__attribute__((address_space(3))) void*)l, 16, 0, 0);
}

// ---------------------------------------------------------------------------
// Kernel 1: Wcat[o][k] = k<256 ? W_lin[o][k] : W_mem[o][k-256]  (bf16 bits)
//           bias[o] = b_lin[o] + b_mem[o]
// ---------------------------------------------------------------------------
__global__ __launch_bounds__(256) void wcat_kernel(
    const float* __restrict__ Wl, const float* __restrict__ bl,
    const float* __restrict__ Wm, const float* __restrict__ bm,
    unsigned short* __restrict__ Wcat, float* __restrict__ bias) {
  const int e = blockIdx.x * 256 + threadIdx.x;
  const int o = e >> 9;
  const int k = e & 511;
  const float w = (k < 256) ? Wl[o * 256 + k] : Wm[o * 256 + (k - 256)];
  Wcat[e] = f2bf(w);
  if (e < 256) bias[e] = bl[e] + bm[e];
}

// ---------------------------------------------------------------------------
// Kernel 2 (fused): out[M,256] = [x | winmean(x)] @ Wcat^T + bias
// 128x128 block tile, 4 waves 2x2, 16 K-chunks of 32.
//   kc 0..7  : A-chunk = bf16(x[:, kc*32 .. +32])       (load+convert+ds_write)
//   kc 8..15 : A-chunk = bf16(means[:, kc*32-256 ..])   (halo re-read, running sum)
// B staged via global_load_lds width-16 from pre-packed bf16 Wcat.
// grid: (1024, 2) x 256 threads
// ---------------------------------------------------------------------------
__global__ __launch_bounds__(256, 4) void fused_kernel(
    const float* __restrict__ x,            // [M, 256] fp32
    const unsigned short* __restrict__ Wc,  // [256, 512] bf16 bits (B^T)
    const float* __restrict__ bias,         // [256]
    float* __restrict__ out) {              // [M, 256] fp32
  __shared__ __align__(16) unsigned short As[128 * 32];
  __shared__ __align__(16) unsigned short Bs[128 * 32];
  const int tid = threadIdx.x;
  const int m0 = blockIdx.x << 7;
  const int n0 = blockIdx.y << 7;
  const int tb0 = m0 & (T_ - 1);   // token index of tile row 0 within its batch
  const int w = tid >> 6;
  const int l = tid & 63;
  const int wr = (w >> 1) << 6;    // wave M offset
  const int wc = (w & 1) << 6;     // wave N offset
  const int lm = l & 15;
  const int kq = (l >> 4) << 3;

  // B staging: 16B chunks, chunk f -> row f/4, col (f%4)*8
  const int f0 = tid, f1 = tid + 256;
  const size_t gb0 = (size_t)(n0 + (f0 >> 2)) * 512 + ((f0 & 3) << 3);
  const size_t gb1 = (size_t)(n0 + (f1 >> 2)) * 512 + ((f1 & 3) << 3);

  // phase-1 A staging: col-pair p_cp (16 pairs), row-group p_g (16 x 8 rows)
  const int p_cp = tid & 15, p_g = tid >> 4;
  // phase-2 A staging: single col q_c (32), row-group q_g (8 x 16 rows)
  const int q_c = tid & 31, q_g = tid >> 5;

  f32x4 acc[4][4];
#pragma unroll
  for (int i = 0; i < 4; ++i)
#pragma unroll
    for (int j = 0; j < 4; ++j) acc[i][j] = (f32x4){0.f, 0.f, 0.f, 0.f};

  for (int kc = 0; kc < 16; ++kc) {
    __syncthreads();  // previous iter's ds_reads done before overwrite
    load_lds16(Wc + gb0 + kc * 32, &Bs[f0 * 8]);
    load_lds16(Wc + gb1 + kc * 32, &Bs[f1 * 8]);

    if (kc < 8) {
      // x part: rows p_g*8 .. +7, cols c..c+31 (pair p_cp)
      const int c = kc * 32;
      const float2* __restrict__ x2 =
          (const float2*)x + (size_t)(m0 + p_g * 8) * 128 + (c >> 1) + p_cp;
      unsigned* __restrict__ As32 = (unsigned*)As;
#pragma unroll
      for (int r = 0; r < 8; ++r) {
        const float2 v = x2[(size_t)r * 128];
        As32[(p_g * 8 + r) * 16 + p_cp] =
            (unsigned)f2bf(v.x) | ((unsigned)f2bf(v.y) << 16);
      }
    } else {
      // means part: window sums over x rows q_g*16-8 .. q_g*16+15, col c+q_c
      const int c = kc * 32 - 256;
      float v[24];
#pragma unroll
      for (int i = 0; i < 24; ++i) {
        const int lr = q_g * 16 - 8 + i;
        const bool ok = (tb0 + lr) >= 0;   // zero outside batch start
        v[i] = ok ? x[(size_t)(m0 + lr) * 256 + c + q_c] : 0.f;
      }
      float s = 0.f;
#pragma unroll
      for (int i = 0; i < 8; ++i) s += v[i];
#pragma unroll
      for (int r = 0; r < 16; ++r) {
        s += v[r + 8];
        const int t = tb0 + q_g * 16 + r;
        const float inv =
            (t >= STRIDE_) ? (1.f / 9.f) : __builtin_amdgcn_rcpf((float)(t + 1));
        As[(q_g * 16 + r) * 32 + q_c] = f2bf(s * inv);
        s -= v[r];
      }
    }
    __syncthreads();  // ds_writes visible + global_load_lds (vmcnt) drained

    bf16x8 a[4], bb[4];
#pragma unroll
    for (int i = 0; i < 4; ++i)
      a[i] = *(const bf16x8*)&As[(wr + i * 16 + lm) * 32 + kq];
#pragma unroll
    for (int j = 0; j < 4; ++j)
      bb[j] = *(const bf16x8*)&Bs[(wc + j * 16 + lm) * 32 + kq];
#pragma unroll
    for (int i = 0; i < 4; ++i)
#pragma unroll
      for (int j = 0; j < 4; ++j)
        acc[i][j] =
            __builtin_amdgcn_mfma_f32_16x16x32_bf16(a[i], bb[j], acc[i][j], 0, 0, 0);
  }

  // epilogue: C/D layout col = l&15, row = (l>>4)*4 + reg
  const int r0 = (l >> 4) << 2;
#pragma unroll
  for (int j = 0; j < 4; ++j) {
    const int o = n0 + wc + j * 16 + lm;
    const float bs = bias[o];
#pragma unroll
    for (int i = 0; i < 4; ++i) {
      const size_t mr = (size_t)(m0 + wr + i * 16 + r0);
#pragma unroll
      for (int r = 0; r < 4; ++r) out[(mr + r) * 256 + o] = acc[i][j][r] + bs;
    }
  }
}

// ---------------------------------------------------------------------------
extern "C" void kernel_launch(void* const* d_in, const int* in_sizes, int n_in,
                              void* d_out, int out_size, void* d_ws, size_t ws_size,
                              hipStream_t stream) {
  const float* x  = (const float*)d_in[0];
  const float* Wl = (const float*)d_in[1];
  const float* bl = (const float*)d_in[2];
  const float* Wm = (const float*)d_in[3];
  const float* bm = (const float*)d_in[4];
  float* out = (float*)d_out;

  // workspace: Wcat [256*512] bf16 (256 KiB) + bias [256] f32 (1 KiB)
  char* ws = (char*)d_ws;
  unsigned short* Wcat = (unsigned short*)ws;
  float* bias = (float*)(ws + (size_t)256 * 512 * 2);

  wcat_kernel<<<512, 256, 0, stream>>>(Wl, bl, Wm, bm, Wcat, bias);
  fused_kernel<<<dim3(M_ / 128, 2), 256, 0, stream>>>(x, Wcat, bias, out);
}

// Round 3
// 270.417 us; speedup vs baseline: 1.2300x; 1.2300x over previous
//
#include <hip/hip_runtime.h>
#include <hip/hip_bf16.h>

// Problem constants (B,T,H fixed by setup_inputs)
#define B_ 16
#define T_ 8192
#define H_ 256
#define M_ (B_ * T_)   // 131072 rows
#define STRIDE_ 8      // window over [max(0,t-8), t], count = min(t+1, 9)

typedef __bf16 bf16x8 __attribute__((ext_vector_type(8)));
typedef float f32x4 __attribute__((ext_vector_type(4)));

// round-to-nearest-even fp32 -> bf16 bits
__device__ __forceinline__ unsigned short f2bf(float f) {
  unsigned u = __builtin_bit_cast(unsigned, f);
  u += 0x7fffu + ((u >> 16) & 1u);
  return (unsigned short)(u >> 16);
}

// async global -> LDS, 16 bytes per lane (global_load_lds_dwordx4)
__device__ __forceinline__ void load_lds16(const void* g, void* l) {
  __builtin_amdgcn_global_load_lds(
      (const __attribute__((address_space(1))) void*)g,
      (__attribute__((address_space(3))) void*)l, 16, 0, 0);
}

// ---------------------------------------------------------------------------
// Kernel 1: build Wpk = 8 per-iteration swizzled LDS images of B^T, bf16.
// Image it: Bs[r][cp][ei] (r<256 out-rows, cp<8 16B-chunks, ei<8) where
//   c = cp ^ (r&7);  k = it*32 + (c&3)*8 + ei + (c<4 ? 0 : 256)
//   value = bf16( k<256 ? W_lin[r][k] : W_mem[r][k-256] )
// Also bias[o] = b_lin[o]+b_mem[o].  131072 elements, grid 512x256.
// ---------------------------------------------------------------------------
__global__ __launch_bounds__(256) void wcat_kernel(
    const float* __restrict__ Wl, const float* __restrict__ bl,
    const float* __restrict__ Wm, const float* __restrict__ bm,
    unsigned short* __restrict__ Wpk, float* __restrict__ bias) {
  const int e = blockIdx.x * 256 + threadIdx.x;
  const int it = e >> 14;
  const int r = (e >> 6) & 255;
  const int col = e & 63;
  const int cp = col >> 3;
  const int ei = col & 7;
  const int c = cp ^ (r & 7);
  const int k = it * 32 + (c & 3) * 8 + ei + ((c < 4) ? 0 : 256);
  const float w = (k < 256) ? Wl[r * 256 + k] : Wm[r * 256 + (k - 256)];
  Wpk[e] = f2bf(w);
  if (e < 256) bias[e] = bl[e] + bm[e];
}

// ---------------------------------------------------------------------------
// Kernel 2 (fused): out[M,256] = [x | winmean(x)] @ Wcat^T + bias
// Block: 64 rows x 256 cols, 256 threads = 4 waves (each 64x64, wc=w*64).
// 8 K-iterations of 64: stages x-chunk (32 cols) AND its means (32 cols)
// from ONE read of x. LDS XOR-swizzled (chunk^=row&7) for conflict-free
// ds_read_b128. B staged via global_load_lds from pre-swizzled Wpk images.
// grid: 2048 x 256
// ---------------------------------------------------------------------------
__global__ __launch_bounds__(256, 3) void fused_kernel(
    const float* __restrict__ x,            // [M, 256] fp32
    const unsigned short* __restrict__ Wpk, // 8 x [256][64] swizzled bf16
    const float* __restrict__ bias,         // [256]
    float* __restrict__ out) {              // [M, 256] fp32
  __shared__ __align__(16) unsigned short As[64 * 64];   //  8 KB swizzled
  __shared__ __align__(16) unsigned short Bs[256 * 64];  // 32 KB swizzled
  const int tid = threadIdx.x;
  const int m0 = blockIdx.x << 6;
  const int tb0 = m0 & (T_ - 1);   // token of tile row 0 within its batch
  const int w = tid >> 6;
  const int l = tid & 63;
  const int wc = w << 6;           // wave N offset (all waves share rows)
  const int lm = l & 15;
  const int kqc = l >> 4;          // k-chunk index within 32 (0..3)

  // A staging: col-pair p (16 pairs of 32-col chunk), row-group g (16 x 4 rows)
  const int p = tid & 15, g = tid >> 4;
  const float2* __restrict__ x2 = (const float2*)x;
  unsigned* __restrict__ As32 = (unsigned*)As;

  f32x4 acc[4][4];
#pragma unroll
  for (int i = 0; i < 4; ++i)
#pragma unroll
    for (int j = 0; j < 4; ++j) acc[i][j] = (f32x4){0.f, 0.f, 0.f, 0.f};

  for (int it = 0; it < 8; ++it) {
    __syncthreads();  // previous iter's ds_reads done before overwrite

    // --- B: copy 32 KB pre-swizzled image (lane-linear, async) ---
    const unsigned short* bsrc = Wpk + (it << 14);
#pragma unroll
    for (int rnd = 0; rnd < 8; ++rnd) {
      const int f = tid + (rnd << 8);
      load_lds16(bsrc + f * 8, &Bs[f * 8]);
    }

    // --- A: read 12 rows of x (8-row halo), emit x-pairs + mean-pairs ---
    float2 v[12];
#pragma unroll
    for (int i = 0; i < 12; ++i) {
      const int rl = (g << 2) - 8 + i;          // local row -8 .. tile end
      float2 val = {0.f, 0.f};
      if (tb0 + rl >= 0)                        // zero before batch start
        val = x2[(size_t)(m0 + rl) * 128 + (it << 4) + p];
      v[i] = val;
    }
    float sx = 0.f, sy = 0.f;
#pragma unroll
    for (int i = 0; i < 8; ++i) { sx += v[i].x; sy += v[i].y; }
#pragma unroll
    for (int rr = 0; rr < 4; ++rr) {
      sx += v[rr + 8].x; sy += v[rr + 8].y;
      const int r = (g << 2) + rr;
      const int t = tb0 + r;
      const float inv =
          (t >= STRIDE_) ? (1.f / 9.f) : __builtin_amdgcn_rcpf((float)(t + 1));
      const unsigned xp =
          (unsigned)f2bf(v[rr + 8].x) | ((unsigned)f2bf(v[rr + 8].y) << 16);
      const unsigned mp =
          (unsigned)f2bf(sx * inv) | ((unsigned)f2bf(sy * inv) << 16);
      const int sw = r & 7;
      As32[r * 32 + (((p >> 2) ^ sw) << 2) + (p & 3)] = xp;        // chunks 0-3
      As32[r * 32 + (((4 + (p >> 2)) ^ sw) << 2) + (p & 3)] = mp;  // chunks 4-7
      sx -= v[rr].x; sy -= v[rr].y;
    }
    __syncthreads();  // ds_writes visible + global_load_lds drained

    // --- MFMA: K=64 in two k-steps of 32 ---
#pragma unroll
    for (int kk = 0; kk < 2; ++kk) {
      const int cc = (kk << 2) + kqc;
      bf16x8 a[4], bb[4];
#pragma unroll
      for (int i = 0; i < 4; ++i) {
        const int R = (i << 4) + lm;
        a[i] = *(const bf16x8*)&As[R * 64 + ((cc ^ (R & 7)) << 3)];
      }
#pragma unroll
      for (int j = 0; j < 4; ++j) {
        const int R = wc + (j << 4) + lm;
        bb[j] = *(const bf16x8*)&Bs[R * 64 + ((cc ^ (R & 7)) << 3)];
      }
#pragma unroll
      for (int i = 0; i < 4; ++i)
#pragma unroll
        for (int j = 0; j < 4; ++j)
          acc[i][j] = __builtin_amdgcn_mfma_f32_16x16x32_bf16(a[i], bb[j],
                                                              acc[i][j], 0, 0, 0);
    }
  }

  // epilogue: C/D layout col = l&15, row = (l>>4)*4 + reg
  const int r0 = (l >> 4) << 2;
#pragma unroll
  for (int j = 0; j < 4; ++j) {
    const int o = wc + (j << 4) + lm;
    const float bs = bias[o];
#pragma unroll
    for (int i = 0; i < 4; ++i) {
      const size_t mr = (size_t)(m0 + (i << 4) + r0);
#pragma unroll
      for (int r = 0; r < 4; ++r) out[(mr + r) * 256 + o] = acc[i][j][r] + bs;
    }
  }
}

// ---------------------------------------------------------------------------
extern "C" void kernel_launch(void* const* d_in, const int* in_sizes, int n_in,
                              void* d_out, int out_size, void* d_ws, size_t ws_size,
                              hipStream_t stream) {
  const float* x  = (const float*)d_in[0];
  const float* Wl = (const float*)d_in[1];
  const float* bl = (const float*)d_in[2];
  const float* Wm = (const float*)d_in[3];
  const float* bm = (const float*)d_in[4];
  float* out = (float*)d_out;

  // workspace: Wpk 8x256x64 bf16 (256 KiB) + bias 256 f32 (1 KiB)
  char* ws = (char*)d_ws;
  unsigned short* Wpk = (unsigned short*)ws;
  float* bias = (float*)(ws + (size_t)8 * 256 * 64 * 2);

  wcat_kernel<<<512, 256, 0, stream>>>(Wl, bl, Wm, bm, Wpk, bias);
  fused_kernel<<<2048, 256, 0, stream>>>(x, Wpk, bias, out);
}